// Round 7
// baseline (265.943 us; speedup 1.0000x reference)
//
#include <hip/hip_runtime.h>
#include <math.h>

// ---------------------------------------------------------------------------
// 2-layer GAT on MI355X.
// R6 -> R7: gemm_dual was latency/imbalance-bound (MfmaUtil 3.4%, occupancy
// 26%): 40% of blocks did the 2x dual pass, 60% the single pass -> straggler
// CUs. Split into two uniform-work kernels (dual for rows<ndst, z-only for
// the rest). Also deleted the attr f32->bf16 pre-pass: L0 GEMMs read f32 and
// convert in-register (VALU was 8% busy; saves ~12us + 51MB traffic).
// ---------------------------------------------------------------------------

#define D 128

typedef __bf16 bf16x8 __attribute__((ext_vector_type(8)));
typedef float f32x4 __attribute__((ext_vector_type(4)));

static __device__ __forceinline__ float lrelu(float x) {
  return x >= 0.f ? x : 0.01f * x;
}
static __device__ __forceinline__ unsigned short f2bf(float v) {
  unsigned int u = __float_as_uint(v);
  u += 0x7fffu + ((u >> 16) & 1u);  // RNE
  return (unsigned short)(u >> 16);
}
static __device__ __forceinline__ float bf2f(unsigned short b) {
  return __uint_as_float((unsigned int)b << 16);
}

static __device__ __forceinline__ float2 loadF2(const float* p) {
  return *(const float2*)p;
}
static __device__ __forceinline__ float2 loadF2(const unsigned short* p) {
  ushort2 t = *(const ushort2*)p;
  return make_float2(bf2f(t.x), bf2f(t.y));
}
static __device__ __forceinline__ void storeF2(float* p, float2 v) {
  *(float2*)p = v;
}
static __device__ __forceinline__ void storeF2(unsigned short* p, float2 v) {
  ushort2 t;
  t.x = f2bf(v.x);
  t.y = f2bf(v.y);
  *(ushort2*)p = t;
}
static __device__ __forceinline__ void storeZi(float* p, float v) { *p = v; }
static __device__ __forceinline__ void storeZi(unsigned short* p, float v) {
  *p = f2bf(v);
}

// A-fragment load: 8 bf16 k-elems, from f32 (in-register cvt) or bf16 store
static __device__ __forceinline__ bf16x8 loadA8(const float* p) {
  float4 v0 = *(const float4*)p;
  float4 v1 = *(const float4*)(p + 4);
  bf16x8 r;
  r[0] = (__bf16)v0.x; r[1] = (__bf16)v0.y;
  r[2] = (__bf16)v0.z; r[3] = (__bf16)v0.w;
  r[4] = (__bf16)v1.x; r[5] = (__bf16)v1.y;
  r[6] = (__bf16)v1.z; r[7] = (__bf16)v1.w;
  return r;
}
static __device__ __forceinline__ bf16x8 loadA8(const unsigned short* p) {
  return *(const bf16x8*)p;
}

// ---- weight f32 -> bf16 (4 matrices of 128x128) ---------------------------
__global__ __launch_bounds__(256) void cvt4_kernel(
    const float* __restrict__ s0, const float* __restrict__ s1,
    const float* __restrict__ s2, const float* __restrict__ s3,
    __bf16* __restrict__ dst) {
  int idx = blockIdx.x * 256 + threadIdx.x;  // 0..65535
  const float* s = (idx < 16384) ? s0
                   : (idx < 32768) ? s1
                   : (idx < 49152) ? s2 : s3;
  dst[idx] = (__bf16)s[idx & 16383];
}

// ---------------- MFMA GEMM tile: rows [r_base, r_end) ---------------------
// z = A@Wb.T (+zs); DUAL adds zd and zi = A@Ub.T. One wave = 16 rows.
// Uniform work per launch (no divergent dual/single blocks).
template <typename AT, typename ZiT, bool DUAL>
__global__ __launch_bounds__(256) void gemm_tile(
    const AT* __restrict__ A, const __bf16* __restrict__ Wb,
    const __bf16* __restrict__ Ub, unsigned short* __restrict__ z,
    ZiT* __restrict__ zi, const float* __restrict__ a,
    float* __restrict__ zs, float* __restrict__ zd, int r_base, int r_end) {
  const int wave = threadIdx.x >> 6;
  const int lane = threadIdx.x & 63;
  const int r0 = r_base + (blockIdx.x * 4 + wave) * 16;
  if (r0 >= r_end) return;
  const int lm = lane & 15;
  const int lk = lane >> 4;

  // A fragments: lane holds A[r0+lm][kt*32 + lk*8 + 0..7]
  bf16x8 af[4];
  const AT* ap = A + (size_t)(r0 + lm) * D + lk * 8;
#pragma unroll
  for (int kt = 0; kt < 4; ++kt) af[kt] = loadA8(ap + kt * 32);

  f32x4 acc[8];
#pragma unroll
  for (int t = 0; t < 8; ++t) acc[t] = (f32x4){0.f, 0.f, 0.f, 0.f};
#pragma unroll
  for (int kt = 0; kt < 4; ++kt) {
#pragma unroll
    for (int t = 0; t < 8; ++t) {
      bf16x8 bf =
          *(const bf16x8*)(Wb + (size_t)(t * 16 + lm) * D + kt * 32 + lk * 8);
      acc[t] = __builtin_amdgcn_mfma_f32_16x16x32_bf16(af[kt], bf, acc[t],
                                                       0, 0, 0);
    }
  }
  // write z (bf16): row = r0 + lk*4 + rr, col = t*16 + lm
#pragma unroll
  for (int t = 0; t < 8; ++t)
#pragma unroll
    for (int rr = 0; rr < 4; ++rr)
      z[(size_t)(r0 + lk * 4 + rr) * D + t * 16 + lm] = f2bf(acc[t][rr]);

  // zs (and zd if DUAL) epilogue from acc
  {
    float a1v[8], a2v[8];
#pragma unroll
    for (int t = 0; t < 8; ++t) {
      a1v[t] = a[t * 16 + lm];
      if constexpr (DUAL) a2v[t] = a[D + t * 16 + lm];
    }
#pragma unroll
    for (int rr = 0; rr < 4; ++rr) {
      float p1 = 0.f, p2 = 0.f;
#pragma unroll
      for (int t = 0; t < 8; ++t) {
        p1 += acc[t][rr] * a1v[t];
        if constexpr (DUAL) p2 += acc[t][rr] * a2v[t];
      }
#pragma unroll
      for (int o = 1; o < 16; o <<= 1) {
        p1 += __shfl_xor(p1, o);
        if constexpr (DUAL) p2 += __shfl_xor(p2, o);
      }
      if (lm == 0) {
        zs[r0 + lk * 4 + rr] = p1;
        if constexpr (DUAL) zd[r0 + lk * 4 + rr] = p2;
      }
    }
  }

  // U pass (zi) for dual rows
  if constexpr (DUAL) {
#pragma unroll
    for (int t = 0; t < 8; ++t) acc[t] = (f32x4){0.f, 0.f, 0.f, 0.f};
#pragma unroll
    for (int kt = 0; kt < 4; ++kt) {
#pragma unroll
      for (int t = 0; t < 8; ++t) {
        bf16x8 bf = *(const bf16x8*)(Ub + (size_t)(t * 16 + lm) * D + kt * 32 +
                                     lk * 8);
        acc[t] = __builtin_amdgcn_mfma_f32_16x16x32_bf16(af[kt], bf, acc[t],
                                                         0, 0, 0);
      }
    }
#pragma unroll
    for (int t = 0; t < 8; ++t)
#pragma unroll
      for (int rr = 0; rr < 4; ++rr)
        storeZi(&zi[(size_t)(r0 + lk * 4 + rr) * D + t * 16 + lm],
                acc[t][rr]);
  }
}

// ---------------- CSR build -------------------------------------------------
__global__ void zero_int_kernel(int* __restrict__ p, int n) {
  int i = blockIdx.x * 256 + threadIdx.x;
  if (i < n) p[i] = 0;
}

__global__ void count_kernel(const int* __restrict__ dst, int* __restrict__ cnt,
                             int E) {
  int i = blockIdx.x * 256 + threadIdx.x;
  if (i < E) atomicAdd(&cnt[dst[i]], 1);
}

__global__ __launch_bounds__(256) void scan_partial(const int* __restrict__ cnt,
                                                    int* __restrict__ part,
                                                    int n) {
  __shared__ int sm[4];
  int base = blockIdx.x * 1024;
  int t = threadIdx.x;
  int s = 0;
#pragma unroll
  for (int i = 0; i < 4; ++i) {
    int idx = base + t + i * 256;
    s += (idx < n) ? cnt[idx] : 0;
  }
  for (int o = 32; o; o >>= 1) s += __shfl_xor(s, o);
  if ((t & 63) == 0) sm[t >> 6] = s;
  __syncthreads();
  if (t == 0) part[blockIdx.x] = sm[0] + sm[1] + sm[2] + sm[3];
}

__global__ void scan_top(int* __restrict__ part, int nb) {
  int t = threadIdx.x;
  int orig = (t < nb) ? part[t] : 0;
  int v = orig;
#pragma unroll
  for (int o = 1; o < 64; o <<= 1) {
    int u = __shfl_up(v, o);
    if (t >= o) v += u;
  }
  if (t < nb) part[t] = v - orig;
}

__global__ __launch_bounds__(256) void scan_final(
    const int* __restrict__ cnt, const int* __restrict__ part,
    int* __restrict__ offs, int* __restrict__ cursor, int n, int total) {
  __shared__ int sm[4];
  int base = blockIdx.x * 1024;
  int t = threadIdx.x;
  int idx = base + t * 4;
  int c0 = (idx + 0 < n) ? cnt[idx + 0] : 0;
  int c1 = (idx + 1 < n) ? cnt[idx + 1] : 0;
  int c2 = (idx + 2 < n) ? cnt[idx + 2] : 0;
  int c3 = (idx + 3 < n) ? cnt[idx + 3] : 0;
  int ts = c0 + c1 + c2 + c3;
  int v = ts;
#pragma unroll
  for (int o = 1; o < 64; o <<= 1) {
    int u = __shfl_up(v, o);
    if ((t & 63) >= o) v += u;
  }
  if ((t & 63) == 63) sm[t >> 6] = v;
  __syncthreads();
  int w = t >> 6;
  int waveoff = 0;
  if (w > 0) waveoff += sm[0];
  if (w > 1) waveoff += sm[1];
  if (w > 2) waveoff += sm[2];
  int run = v - ts + waveoff + part[blockIdx.x];
  if (idx + 0 < n) { offs[idx + 0] = run; cursor[idx + 0] = run; run += c0; }
  if (idx + 1 < n) { offs[idx + 1] = run; cursor[idx + 1] = run; run += c1; }
  if (idx + 2 < n) { offs[idx + 2] = run; cursor[idx + 2] = run; run += c2; }
  if (idx + 3 < n) { offs[idx + 3] = run; cursor[idx + 3] = run; run += c3; }
  if (blockIdx.x == 0 && t == 0) offs[n] = total;
}

// scatter + fused edge-logit, packed 8B write: csr[p] = (src, bits(e))
__global__ void scatter_kernel(const int* __restrict__ src,
                               const int* __restrict__ dst,
                               const float* __restrict__ dE,
                               const float* __restrict__ zs,
                               const float* __restrict__ zd,
                               const float* __restrict__ V,
                               const float* __restrict__ a,
                               int* __restrict__ cursor,
                               int2* __restrict__ csr, int E) {
  int i = blockIdx.x * 256 + threadIdx.x;
  if (i < E) {
    int di = dst[i];
    int si = src[i];
    int p = atomicAdd(&cursor[di], 1);
    float vc = V[0] * a[2 * D];
    float e = lrelu(zs[si] + zd[di] + dE[i] * vc);
    csr[p] = make_int2(si, __float_as_int(e));
  }
}

// ---------------- per-dst: softmax + weighted accumulate -------------------
template <typename OT>
__global__ __launch_bounds__(256) void gat_perdst(
    const unsigned short* __restrict__ z, const int2* __restrict__ csr,
    const int* __restrict__ offs, const OT* __restrict__ ziin,
    OT* __restrict__ hout, int nd) {
  int n = blockIdx.x * 4 + (threadIdx.x >> 6);
  if (n >= nd) return;
  int lane = threadIdx.x & 63;
  int beg = offs[n], end = offs[n + 1];

  float m = -INFINITY;
  for (int j = beg + lane; j < end; j += 64)
    m = fmaxf(m, __int_as_float(csr[j].y));
  for (int o = 32; o; o >>= 1) m = fmaxf(m, __shfl_xor(m, o));

  float s = 0.f;
  float2 acc = make_float2(0.f, 0.f);
  const unsigned short* zp = z + lane * 2;
  int j = beg;
  for (; j + 8 <= end; j += 8) {
    int2 pr[8];
#pragma unroll
    for (int u = 0; u < 8; ++u) pr[u] = csr[j + u];
    float2 zv[8];
#pragma unroll
    for (int u = 0; u < 8; ++u) zv[u] = loadF2(zp + (size_t)pr[u].x * D);
#pragma unroll
    for (int u = 0; u < 8; ++u) {
      float w = __expf(__int_as_float(pr[u].y) - m);
      s += w;
      acc.x += w * zv[u].x;
      acc.y += w * zv[u].y;
    }
  }
  for (; j < end; ++j) {
    int2 pr = csr[j];
    float w = __expf(__int_as_float(pr.y) - m);
    float2 zv = loadF2(zp + (size_t)pr.x * D);
    s += w;
    acc.x += w * zv.x;
    acc.y += w * zv.y;
  }
  float inv = (s > 0.f) ? 1.f / s : 0.f;
  float2 ziv = loadF2(ziin + (size_t)n * D + lane * 2);
  float2 o2;
  o2.x = fmaxf(ziv.x + acc.x * inv, 0.f);
  o2.y = fmaxf(ziv.y + acc.y * inv, 0.f);
  storeF2(hout + (size_t)n * D + lane * 2, o2);
}

// ---------------------------------------------------------------------------
static void build_csr(const int* dst, int nd, int E, int* cnt, int* offs,
                      int* cursor, int* part, hipStream_t stream) {
  zero_int_kernel<<<(nd + 255) / 256, 256, 0, stream>>>(cnt, nd);
  count_kernel<<<(E + 255) / 256, 256, 0, stream>>>(dst, cnt, E);
  int nb = (nd + 1023) / 1024;  // <= 40
  scan_partial<<<nb, 256, 0, stream>>>(cnt, part, nd);
  scan_top<<<1, 64, 0, stream>>>(part, nb);
  scan_final<<<nb, 256, 0, stream>>>(cnt, part, offs, cursor, nd, E);
}

extern "C" void kernel_launch(void* const* d_in, const int* in_sizes, int n_in,
                              void* d_out, int out_size, void* d_ws,
                              size_t ws_size, hipStream_t stream) {
  const float* attr = (const float*)d_in[0];
  const float* d0 = (const float*)d_in[1];
  const float* d1 = (const float*)d_in[2];
  const int* src0 = (const int*)d_in[3];
  const int* dst0 = (const int*)d_in[4];
  const int* src1 = (const int*)d_in[5];
  const int* dst1 = (const int*)d_in[6];
  const float* W0 = (const float*)d_in[9];
  const float* U0 = (const float*)d_in[10];
  const float* V0 = (const float*)d_in[11];
  const float* a0 = (const float*)d_in[12];
  const float* W1 = (const float*)d_in[13];
  const float* U1 = (const float*)d_in[14];
  const float* V1 = (const float*)d_in[15];
  const float* a1 = (const float*)d_in[16];

  const int N0 = in_sizes[0] / D;  // 100000
  const int E0 = in_sizes[1];      // 640000
  const int E1 = in_sizes[2];      // 320000
  const int ND0 = 40000;
  const int ND1 = 20000;

  char* p = (char*)d_ws;
  auto alloc = [&](size_t bytes) {
    char* q = p;
    p += (bytes + 255) & ~(size_t)255;
    return q;
  };
  unsigned short* z = (unsigned short*)alloc((size_t)N0 * D * 2);  // 25.6MB
  int2* csr = (int2*)alloc((size_t)E0 * 8);                        // 5.12MB
  unsigned short* h1b = (unsigned short*)alloc((size_t)ND0 * D * 2);  // 10.2MB
  float* zs = (float*)alloc((size_t)N0 * 4);
  float* zd = (float*)alloc((size_t)N0 * 4);
  int* offs = (int*)alloc((size_t)(ND0 + 1) * 4);
  int* cnt = (int*)alloc((size_t)ND0 * 4);
  int* cursor = (int*)alloc((size_t)ND0 * 4);
  int* part = (int*)alloc((size_t)64 * 4);
  __bf16* wb = (__bf16*)alloc((size_t)4 * D * D * 2);  // W0,U0,W1,U1 bf16
  (void)n_in;
  (void)out_size;
  (void)ws_size;

  float* out = (float*)d_out;

  cvt4_kernel<<<256, 256, 0, stream>>>(W0, U0, W1, U1, wb);
  const __bf16* W0b = wb;
  const __bf16* U0b = wb + 16384;
  const __bf16* W1b = wb + 32768;
  const __bf16* U1b = wb + 49152;

  // ---- layer 0: A = attr (f32, converted in-register) ----
  // dual rows [0, ND0): z+zs+zd+zi(bf16 in d_out); z-only rows [ND0, N0)
  gemm_tile<float, unsigned short, true>
      <<<(ND0 + 63) / 64, 256, 0, stream>>>(attr, W0b, U0b, z,
                                            (unsigned short*)d_out, a0, zs, zd,
                                            0, ND0);
  gemm_tile<float, unsigned short, false>
      <<<(N0 - ND0 + 63) / 64, 256, 0, stream>>>(attr, W0b, nullptr, z,
                                                 nullptr, a0, zs, nullptr, ND0,
                                                 N0);
  build_csr(dst0, ND0, E0, cnt, offs, cursor, part, stream);
  scatter_kernel<<<(E0 + 255) / 256, 256, 0, stream>>>(
      src0, dst0, d0, zs, zd, V0, a0, cursor, csr, E0);
  gat_perdst<unsigned short><<<(ND0 + 3) / 4, 256, 0, stream>>>(
      z, csr, offs, (const unsigned short*)d_out, h1b, ND0);

  // ---- layer 1: A = h1b (bf16) ----
  gemm_tile<unsigned short, float, true>
      <<<(ND1 + 63) / 64, 256, 0, stream>>>(h1b, W1b, U1b, z, out, a1, zs, zd,
                                            0, ND1);
  gemm_tile<unsigned short, float, false>
      <<<(ND0 - ND1 + 63) / 64, 256, 0, stream>>>(h1b, W1b, nullptr, z,
                                                  nullptr, a1, zs, nullptr,
                                                  ND1, ND0);
  build_csr(dst1, ND1, E1, cnt, offs, cursor, part, stream);
  scatter_kernel<<<(E1 + 255) / 256, 256, 0, stream>>>(
      src1, dst1, d1, zs, zd, V1, a1, cursor, csr, E1);
  gat_perdst<float><<<(ND1 + 3) / 4, 256, 0, stream>>>(z, csr, offs, out, out,
                                                       ND1);
}